// Round 5
// baseline (1082.612 us; speedup 1.0000x reference)
//
#include <hip/hip_runtime.h>

// Problem constants (hardcoded from reference)
#define BD   32768               // boards
#define NPG  54                  // nodes per graph
#define NN   (BD * NPG)          // 1,769,472 nodes
#define NE   (BD * 144)          // 4,718,592 edges
#define DIN  16
#define DH   32
#define GLOBF 16
#define TB   32                  // boards per block in final kernel
#define RB   256                 // nodes per dst bucket (dst>>8)
#define NBK  (NN / RB)           // 6912 buckets
#define MB   4                   // buckets per conv block
#define STR1 17                  // LDS row stride (floats) conv1 (odd -> bank spread)
#define STR2 5                   // LDS row stride conv2
#define SRCM 0x1FFFFFu           // 21-bit src mask (NN < 2^21)

// ---------------------------------------------------------------------------
// Pass 1: histogram of destination buckets
// ---------------------------------------------------------------------------
__global__ __launch_bounds__(256) void k_hist(const int* __restrict__ ei,
                                              unsigned* __restrict__ hist) {
  unsigned e = blockIdx.x * 256u + threadIdx.x;          // NE threads exactly
  unsigned d = (unsigned)ei[NE + e];
  atomicAdd(&hist[d >> 8], 1u);
}

// ---------------------------------------------------------------------------
// Pass 2: exclusive scan of 6912 bucket counts (single 1024-thread block)
// ---------------------------------------------------------------------------
__global__ __launch_bounds__(1024) void k_scan(const unsigned* __restrict__ hist,
                                               unsigned* __restrict__ base,
                                               unsigned* __restrict__ cursor) {
  __shared__ unsigned s[1024];
  const int tid = threadIdx.x;
  unsigned loc[7];
  unsigned run = 0;
#pragma unroll
  for (int j = 0; j < 7; ++j) {                          // 1024*7 >= 6912
    int idx = tid * 7 + j;
    unsigned v = (idx < NBK) ? hist[idx] : 0u;
    loc[j] = run; run += v;
  }
  s[tid] = run;
  __syncthreads();
  for (int off = 1; off < 1024; off <<= 1) {             // Hillis-Steele inclusive
    unsigned t = (tid >= off) ? s[tid - off] : 0u;
    __syncthreads();
    s[tid] += t;
    __syncthreads();
  }
  unsigned cb = tid ? s[tid - 1] : 0u;
#pragma unroll
  for (int j = 0; j < 7; ++j) {
    int idx = tid * 7 + j;
    if (idx < NBK) { unsigned b = cb + loc[j]; base[idx] = b; cursor[idx] = b; }
  }
  if (tid == 1023) base[NBK] = s[1023];                  // = NE
}

// ---------------------------------------------------------------------------
// Pass 3: place edge records bucket-sorted: {src | dstLo<<21, w}  (8 B each)
// ---------------------------------------------------------------------------
__global__ __launch_bounds__(256) void k_place(const int* __restrict__ ei,
                                               const float* __restrict__ ea,
                                               unsigned* __restrict__ cursor,
                                               uint2* __restrict__ rec) {
  unsigned e = blockIdx.x * 256u + threadIdx.x;
  unsigned s = (unsigned)ei[e];
  unsigned d = (unsigned)ei[NE + e];
  float w = ea[e];
  unsigned b = d >> 8;
  unsigned pos = atomicAdd(&cursor[b], 1u);
  rec[pos] = make_uint2(s | ((d & 255u) << 21), __float_as_uint(w));
}

// ---------------------------------------------------------------------------
// Conv1 (fused): MB dst-buckets per block. Per bucket: accumulate aggr1 tile
// in LDS via branch-free 4-deep gather pipeline, then the fused node
// transform (weights read from LDS):
// h1 = relu(aggr1@W1_rel + x@W1_root + b1), z2 = h1@W2_rel, r2 = h1@W2_root+b2
// ---------------------------------------------------------------------------
__global__ __launch_bounds__(256, 4) void k_conv1(
    const uint2* __restrict__ rec, const unsigned* __restrict__ base,
    const float* __restrict__ x,
    const float* __restrict__ W1_rel, const float* __restrict__ b1,
    const float* __restrict__ W1_root,
    const float* __restrict__ W2_rel, const float* __restrict__ b2,
    const float* __restrict__ W2_root,
    float* __restrict__ z2, float* __restrict__ r2) {
  __shared__ float acc[RB * STR1];                       // 17408 B
  __shared__ float sw[1316];                             // 5264 B weights
  float* sW1rel  = sw;            // [512] i*32+j
  float* sW1root = sw + 512;      // [512]
  float* sW2rel  = sw + 1024;     // [128] j*4+k
  float* sW2root = sw + 1152;     // [128]
  float* sb1     = sw + 1280;     // [32]
  float* sb2     = sw + 1312;     // [4]

  const int tid = threadIdx.x;
  // weight preload (once per block)
  for (int i = tid; i < 512; i += 256) { sW1rel[i] = W1_rel[i]; sW1root[i] = W1_root[i]; }
  if (tid < 128) { sW2rel[tid] = W2_rel[tid]; sW2root[tid] = W2_root[tid]; }
  if (tid < 32)  sb1[tid] = b1[tid];
  if (tid < 4)   sb2[tid] = b2[tid];
  for (int i = tid; i < RB * STR1; i += 256) acc[i] = 0.f;
  __syncthreads();

  const unsigned p4 = (tid & 3u) * 4;                    // this lane's 16B slice
  const unsigned g  = tid >> 2;                          // lane-group 0..63

  for (int m = 0; m < MB; ++m) {
    const unsigned bk = blockIdx.x * MB + m;
    const unsigned r0 = base[bk], r1 = base[bk + 1];
    const unsigned last = r1 - 1u;                       // r1>r0 whenever loop runs

    // branch-free 4-deep gather-accumulate (OOB -> clamp index, zero weight)
    for (unsigned ib = r0 + g * 4u; ib < r1; ib += 256u) {
      const unsigned j1 = ib + 1u, j2 = ib + 2u, j3 = ib + 3u;
      const bool q1 = j1 < r1, q2 = j2 < r1, q3 = j3 < r1;
      uint2 ra = rec[ib];
      uint2 rb = rec[q1 ? j1 : last];
      uint2 rc = rec[q2 ? j2 : last];
      uint2 rd = rec[q3 ? j3 : last];
      const float4 va = *reinterpret_cast<const float4*>(x + (size_t)(ra.x & SRCM) * 16 + p4);
      const float4 vb = *reinterpret_cast<const float4*>(x + (size_t)(rb.x & SRCM) * 16 + p4);
      const float4 vc = *reinterpret_cast<const float4*>(x + (size_t)(rc.x & SRCM) * 16 + p4);
      const float4 vd = *reinterpret_cast<const float4*>(x + (size_t)(rd.x & SRCM) * 16 + p4);
      const float wa = __uint_as_float(ra.y);
      const float wb = q1 ? __uint_as_float(rb.y) : 0.f;
      const float wc = q2 ? __uint_as_float(rc.y) : 0.f;
      const float wd = q3 ? __uint_as_float(rd.y) : 0.f;
      float* da = acc + (ra.x >> 21) * STR1 + p4;
      float* db = acc + (rb.x >> 21) * STR1 + p4;
      float* dc = acc + (rc.x >> 21) * STR1 + p4;
      float* dd = acc + (rd.x >> 21) * STR1 + p4;
      atomicAdd(da + 0, va.x * wa); atomicAdd(da + 1, va.y * wa);
      atomicAdd(da + 2, va.z * wa); atomicAdd(da + 3, va.w * wa);
      atomicAdd(db + 0, vb.x * wb); atomicAdd(db + 1, vb.y * wb);
      atomicAdd(db + 2, vb.z * wb); atomicAdd(db + 3, vb.w * wb);
      atomicAdd(dc + 0, vc.x * wc); atomicAdd(dc + 1, vc.y * wc);
      atomicAdd(dc + 2, vc.z * wc); atomicAdd(dc + 3, vc.w * wc);
      atomicAdd(dd + 0, vd.x * wd); atomicAdd(dd + 1, vd.y * wd);
      atomicAdd(dd + 2, vd.z * wd); atomicAdd(dd + 3, vd.w * wd);
    }
    __syncthreads();                                     // atomics complete

    // pull this thread's aggr row, then release the tile
    float a[16];
#pragma unroll
    for (int i = 0; i < 16; ++i) a[i] = acc[tid * STR1 + i];
    __syncthreads();                                     // reads done
    if (m + 1 < MB)
      for (int i = tid; i < RB * STR1; i += 256) acc[i] = 0.f;  // re-zero for next

    // fused node transform: node n = bk*RB + tid
    size_t n = (size_t)bk * RB + tid;
    float xv[16];
    {
      const float4* xp = reinterpret_cast<const float4*>(x + n * 16);
#pragma unroll
      for (int q = 0; q < 4; ++q) {
        float4 t2 = xp[q];
        xv[4*q+0] = t2.x; xv[4*q+1] = t2.y; xv[4*q+2] = t2.z; xv[4*q+3] = t2.w;
      }
    }
    float h[DH];
#pragma unroll
    for (int j = 0; j < DH; ++j) h[j] = sb1[j];
#pragma unroll
    for (int i = 0; i < DIN; ++i) {
      float ai = a[i], xi = xv[i];
#pragma unroll
      for (int j = 0; j < DH; ++j)
        h[j] = fmaf(ai, sW1rel[i * DH + j], fmaf(xi, sW1root[i * DH + j], h[j]));
    }
#pragma unroll
    for (int j = 0; j < DH; ++j) h[j] = fmaxf(h[j], 0.f);

    float z[4] = {0.f, 0.f, 0.f, 0.f};
    float r[4] = {sb2[0], sb2[1], sb2[2], sb2[3]};
#pragma unroll
    for (int j = 0; j < DH; ++j) {
      float hj = h[j];
#pragma unroll
      for (int k = 0; k < 4; ++k) {
        z[k] = fmaf(hj, sW2rel[j * 4 + k], z[k]);
        r[k] = fmaf(hj, sW2root[j * 4 + k], r[k]);
      }
    }
    *reinterpret_cast<float4*>(z2 + n * 4) = make_float4(z[0], z[1], z[2], z[3]);
    *reinterpret_cast<float4*>(r2 + n * 4) = make_float4(r[0], r[1], r[2], r[3]);
    if (m + 1 < MB) __syncthreads();                     // zero visible before next gather
  }
}

// ---------------------------------------------------------------------------
// Conv2 (fused): MB dst-buckets per block, 4 lanes per record, branch-free
// 4-deep pipeline; embeds = relu(aggr2 + r2).
// ---------------------------------------------------------------------------
__global__ __launch_bounds__(256, 4) void k_conv2(
    const uint2* __restrict__ rec, const unsigned* __restrict__ base,
    const float* __restrict__ z2, const float* __restrict__ r2,
    float* __restrict__ embeds) {
  __shared__ float acc[RB * STR2];                       // 5120 B
  const int tid = threadIdx.x;
  for (int i = tid; i < RB * STR2; i += 256) acc[i] = 0.f;
  __syncthreads();

  const unsigned p = tid & 3u;                           // this lane's dword
  const unsigned g = tid >> 2;

  for (int m = 0; m < MB; ++m) {
    const unsigned bk = blockIdx.x * MB + m;
    const unsigned r0 = base[bk], r1 = base[bk + 1];
    const unsigned last = r1 - 1u;

    for (unsigned ib = r0 + g * 4u; ib < r1; ib += 256u) {
      const unsigned j1 = ib + 1u, j2 = ib + 2u, j3 = ib + 3u;
      const bool q1 = j1 < r1, q2 = j2 < r1, q3 = j3 < r1;
      uint2 ra = rec[ib];
      uint2 rb = rec[q1 ? j1 : last];
      uint2 rc = rec[q2 ? j2 : last];
      uint2 rd = rec[q3 ? j3 : last];
      float va = z2[(size_t)(ra.x & SRCM) * 4 + p];
      float vb = z2[(size_t)(rb.x & SRCM) * 4 + p];
      float vc = z2[(size_t)(rc.x & SRCM) * 4 + p];
      float vd = z2[(size_t)(rd.x & SRCM) * 4 + p];
      const float wa = __uint_as_float(ra.y);
      const float wb = q1 ? __uint_as_float(rb.y) : 0.f;
      const float wc = q2 ? __uint_as_float(rc.y) : 0.f;
      const float wd = q3 ? __uint_as_float(rd.y) : 0.f;
      atomicAdd(&acc[(ra.x >> 21) * STR2 + p], va * wa);
      atomicAdd(&acc[(rb.x >> 21) * STR2 + p], vb * wb);
      atomicAdd(&acc[(rc.x >> 21) * STR2 + p], vc * wc);
      atomicAdd(&acc[(rd.x >> 21) * STR2 + p], vd * wd);
    }
    __syncthreads();

    size_t n = (size_t)bk * RB + tid;
    float a0 = acc[tid * STR2 + 0], a1 = acc[tid * STR2 + 1];
    float a2 = acc[tid * STR2 + 2], a3 = acc[tid * STR2 + 3];
    __syncthreads();
    if (m + 1 < MB)
      for (int i = tid; i < RB * STR2; i += 256) acc[i] = 0.f;

    const float4 rr = *reinterpret_cast<const float4*>(r2 + n * 4);
    float4 o;
    o.x = fmaxf(a0 + rr.x, 0.f);
    o.y = fmaxf(a1 + rr.y, 0.f);
    o.z = fmaxf(a2 + rr.z, 0.f);
    o.w = fmaxf(a3 + rr.w, 0.f);
    *reinterpret_cast<float4*>(embeds + n * 4) = o;
    if (m + 1 < MB) __syncthreads();
  }
}

// ---------------------------------------------------------------------------
// Final: per-board  vec = concat(embeds[b,216], gMLP(globalFeats[b]))  [232]
//        out = relu(vec@Wo1+bo1) -> relu(@Wo2+bo2) -> @Wo3+bo3  [64]
// ---------------------------------------------------------------------------
__global__ __launch_bounds__(256) void k_final(
    const float* __restrict__ embeds, const float* __restrict__ gfeat,
    const float* __restrict__ Wg1, const float* __restrict__ bg1,
    const float* __restrict__ Wg2, const float* __restrict__ bg2,
    const float* __restrict__ Wg3, const float* __restrict__ bg3,
    const float* __restrict__ Wo1, const float* __restrict__ bo1,
    const float* __restrict__ Wo2, const float* __restrict__ bo2,
    const float* __restrict__ Wo3, const float* __restrict__ bo3,
    float* __restrict__ out) {
  __shared__ float smem[TB * 232 + TB * 128];   // 46080 B
  float* svec  = smem;             // [TB][232]
  float* sbuf1 = smem + TB * 232;  // [TB][128]
  float* sbuf2 = smem;             // alias svec (dead after layer 1)

  const int tid = threadIdx.x;
  const int b0  = blockIdx.x * TB;

  // stage embeds (already relu'd)
  {
    const size_t gbase = (size_t)b0 * 216;
    for (int idx = tid; idx < TB * 216; idx += 256) {
      int b = idx / 216;
      int k = idx - b * 216;
      svec[b * 232 + k] = embeds[gbase + idx];
    }
  }
  // tiny global-feature MLP: 16 -> 8 -> 8 -> 16 (relu each)
  if (tid < TB) {
    const float* gf = gfeat + (size_t)(b0 + tid) * GLOBF;
    float gin[16];
#pragma unroll
    for (int i = 0; i < 16; ++i) gin[i] = gf[i];
    float g1[8];
#pragma unroll
    for (int j = 0; j < 8; ++j) {
      float acc = bg1[j];
#pragma unroll
      for (int i = 0; i < 16; ++i) acc = fmaf(gin[i], Wg1[i * 8 + j], acc);
      g1[j] = fmaxf(acc, 0.f);
    }
    float g2[8];
#pragma unroll
    for (int j = 0; j < 8; ++j) {
      float acc = bg2[j];
#pragma unroll
      for (int i = 0; i < 8; ++i) acc = fmaf(g1[i], Wg2[i * 8 + j], acc);
      g2[j] = fmaxf(acc, 0.f);
    }
#pragma unroll
    for (int j = 0; j < 16; ++j) {
      float acc = bg3[j];
#pragma unroll
      for (int i = 0; i < 8; ++i) acc = fmaf(g2[i], Wg3[i * 16 + j], acc);
      svec[tid * 232 + 216 + j] = fmaxf(acc, 0.f);
    }
  }
  __syncthreads();

  const int c0 = (tid & 31) * 4;   // output column base (0..124)
  const int rb = (tid >> 5) * 4;   // board base within tile (0..28)

  // layer 1: [TB,232] @ [232,128]
  {
    float acc[4][4];
#pragma unroll
    for (int r = 0; r < 4; ++r)
#pragma unroll
      for (int c = 0; c < 4; ++c) acc[r][c] = 0.f;
#pragma unroll 4
    for (int i = 0; i < 232; ++i) {
      const float4 w = *reinterpret_cast<const float4*>(Wo1 + (size_t)i * 128 + c0);
#pragma unroll
      for (int r = 0; r < 4; ++r) {
        float v = svec[(rb + r) * 232 + i];
        acc[r][0] = fmaf(v, w.x, acc[r][0]);
        acc[r][1] = fmaf(v, w.y, acc[r][1]);
        acc[r][2] = fmaf(v, w.z, acc[r][2]);
        acc[r][3] = fmaf(v, w.w, acc[r][3]);
      }
    }
    const float4 bv = *reinterpret_cast<const float4*>(bo1 + c0);
#pragma unroll
    for (int r = 0; r < 4; ++r) {
      float4 o;
      o.x = fmaxf(acc[r][0] + bv.x, 0.f);
      o.y = fmaxf(acc[r][1] + bv.y, 0.f);
      o.z = fmaxf(acc[r][2] + bv.z, 0.f);
      o.w = fmaxf(acc[r][3] + bv.w, 0.f);
      *reinterpret_cast<float4*>(sbuf1 + (rb + r) * 128 + c0) = o;
    }
  }
  __syncthreads();

  // layer 2: [TB,128] @ [128,128]
  {
    float acc[4][4];
#pragma unroll
    for (int r = 0; r < 4; ++r)
#pragma unroll
      for (int c = 0; c < 4; ++c) acc[r][c] = 0.f;
#pragma unroll 4
    for (int i = 0; i < 128; ++i) {
      const float4 w = *reinterpret_cast<const float4*>(Wo2 + (size_t)i * 128 + c0);
#pragma unroll
      for (int r = 0; r < 4; ++r) {
        float v = sbuf1[(rb + r) * 128 + i];
        acc[r][0] = fmaf(v, w.x, acc[r][0]);
        acc[r][1] = fmaf(v, w.y, acc[r][1]);
        acc[r][2] = fmaf(v, w.z, acc[r][2]);
        acc[r][3] = fmaf(v, w.w, acc[r][3]);
      }
    }
    const float4 bv = *reinterpret_cast<const float4*>(bo2 + c0);
#pragma unroll
    for (int r = 0; r < 4; ++r) {
      float4 o;
      o.x = fmaxf(acc[r][0] + bv.x, 0.f);
      o.y = fmaxf(acc[r][1] + bv.y, 0.f);
      o.z = fmaxf(acc[r][2] + bv.z, 0.f);
      o.w = fmaxf(acc[r][3] + bv.w, 0.f);
      *reinterpret_cast<float4*>(sbuf2 + (rb + r) * 128 + c0) = o;
    }
  }
  __syncthreads();

  // layer 3: [TB,128] @ [128,64] -> global out
  {
    const int c2 = (tid & 31) * 2;   // 0..62
    float acc[4][2];
#pragma unroll
    for (int r = 0; r < 4; ++r) { acc[r][0] = 0.f; acc[r][1] = 0.f; }
#pragma unroll 4
    for (int i = 0; i < 128; ++i) {
      const float2 w = *reinterpret_cast<const float2*>(Wo3 + (size_t)i * 64 + c2);
#pragma unroll
      for (int r = 0; r < 4; ++r) {
        float v = sbuf2[(rb + r) * 128 + i];
        acc[r][0] = fmaf(v, w.x, acc[r][0]);
        acc[r][1] = fmaf(v, w.y, acc[r][1]);
      }
    }
    const float2 bv = *reinterpret_cast<const float2*>(bo3 + c2);
#pragma unroll
    for (int r = 0; r < 4; ++r) {
      float2 o;
      o.x = acc[r][0] + bv.x;
      o.y = acc[r][1] + bv.y;
      *reinterpret_cast<float2*>(out + (size_t)(b0 + rb + r) * 64 + c2) = o;
    }
  }
}

// ---------------------------------------------------------------------------
extern "C" void kernel_launch(void* const* d_in, const int* in_sizes, int n_in,
                              void* d_out, int out_size, void* d_ws, size_t ws_size,
                              hipStream_t stream) {
  const float* x      = (const float*)d_in[0];
  const int*   ei     = (const int*)d_in[1];
  const float* ea     = (const float*)d_in[2];
  const float* gfeat  = (const float*)d_in[3];
  // d_in[4] = isTrain (0 at inference; dropout is identity)
  const float* W1_rel = (const float*)d_in[5];
  const float* b1     = (const float*)d_in[6];
  const float* W1_root= (const float*)d_in[7];
  const float* W2_rel = (const float*)d_in[8];
  const float* b2     = (const float*)d_in[9];
  const float* W2_root= (const float*)d_in[10];
  const float* Wg1 = (const float*)d_in[11];
  const float* bg1 = (const float*)d_in[12];
  const float* Wg2 = (const float*)d_in[13];
  const float* bg2 = (const float*)d_in[14];
  const float* Wg3 = (const float*)d_in[15];
  const float* bg3 = (const float*)d_in[16];
  const float* Wo1 = (const float*)d_in[17];
  const float* bo1 = (const float*)d_in[18];
  const float* Wo2 = (const float*)d_in[19];
  const float* bo2 = (const float*)d_in[20];
  const float* Wo3 = (const float*)d_in[21];
  const float* bo3 = (const float*)d_in[22];
  float* outp = (float*)d_out;

  // workspace layout (~123 MB total)
  uint2*    rec    = (uint2*)d_ws;                       // NE * 8 B
  float*    z2     = (float*)(rec + NE);                 // NN*4 f
  float*    r2     = z2 + (size_t)NN * 4;                // NN*4 f
  float*    embeds = r2 + (size_t)NN * 4;                // NN*4 f
  unsigned* hist   = (unsigned*)(embeds + (size_t)NN * 4); // NBK
  unsigned* base   = hist + NBK;                         // NBK+1
  unsigned* cursor = base + NBK + 1;                     // NBK

  hipMemsetAsync(hist, 0, NBK * sizeof(unsigned), stream);
  k_hist <<<NE / 256, 256, 0, stream>>>(ei, hist);
  k_scan <<<1, 1024, 0, stream>>>(hist, base, cursor);
  k_place<<<NE / 256, 256, 0, stream>>>(ei, ea, cursor, rec);
  k_conv1<<<NBK / MB, 256, 0, stream>>>(rec, base, x, W1_rel, b1, W1_root,
                                        W2_rel, b2, W2_root, z2, r2);
  k_conv2<<<NBK / MB, 256, 0, stream>>>(rec, base, z2, r2, embeds);
  k_final<<<BD / TB, 256, 0, stream>>>(embeds, gfeat,
                                       Wg1, bg1, Wg2, bg2, Wg3, bg3,
                                       Wo1, bo1, Wo2, bo2, Wo3, bo3, outp);
}

// Round 6
// 1020.335 us; speedup vs baseline: 1.0610x; 1.0610x over previous
//
#include <hip/hip_runtime.h>

// Problem constants (hardcoded from reference)
#define BD   32768               // boards
#define NPG  54                  // nodes per graph
#define NN   (BD * NPG)          // 1,769,472 nodes
#define NE   (BD * 144)          // 4,718,592 edges
#define DIN  16
#define DH   32
#define GLOBF 16
#define TB   32                  // boards per block in final kernel
#define RB   256                 // nodes per dst bucket (dst>>8)
#define NBK  (NN / RB)           // 6912 buckets
#define RB2  1024                // nodes per conv2 super-bucket
#define NBK2 (NN / RB2)          // 1728
#define STR1 17                  // LDS row stride (floats) conv1
#define STR2 5                   // LDS row stride conv2
#define SRCM 0x1FFFFFu           // 21-bit src mask (NN < 2^21)

// ---------------------------------------------------------------------------
// Pass 1: histogram of destination buckets
// ---------------------------------------------------------------------------
__global__ __launch_bounds__(256) void k_hist(const int* __restrict__ ei,
                                              unsigned* __restrict__ hist) {
  unsigned e = blockIdx.x * 256u + threadIdx.x;          // NE threads exactly
  unsigned d = (unsigned)ei[NE + e];
  atomicAdd(&hist[d >> 8], 1u);
}

// ---------------------------------------------------------------------------
// Pass 2: exclusive scan of 6912 bucket counts (single 1024-thread block)
// ---------------------------------------------------------------------------
__global__ __launch_bounds__(1024) void k_scan(const unsigned* __restrict__ hist,
                                               unsigned* __restrict__ base,
                                               unsigned* __restrict__ cursor) {
  __shared__ unsigned s[1024];
  const int tid = threadIdx.x;
  unsigned loc[7];
  unsigned run = 0;
#pragma unroll
  for (int j = 0; j < 7; ++j) {                          // 1024*7 >= 6912
    int idx = tid * 7 + j;
    unsigned v = (idx < NBK) ? hist[idx] : 0u;
    loc[j] = run; run += v;
  }
  s[tid] = run;
  __syncthreads();
  for (int off = 1; off < 1024; off <<= 1) {             // Hillis-Steele inclusive
    unsigned t = (tid >= off) ? s[tid - off] : 0u;
    __syncthreads();
    s[tid] += t;
    __syncthreads();
  }
  unsigned cb = tid ? s[tid - 1] : 0u;
#pragma unroll
  for (int j = 0; j < 7; ++j) {
    int idx = tid * 7 + j;
    if (idx < NBK) { unsigned b = cb + loc[j]; base[idx] = b; cursor[idx] = b; }
  }
  if (tid == 1023) base[NBK] = s[1023];                  // = NE
}

// ---------------------------------------------------------------------------
// Pass 3: place edge records bucket-sorted: {src | dstLo<<21, w}  (8 B each)
// ---------------------------------------------------------------------------
__global__ __launch_bounds__(256) void k_place(const int* __restrict__ ei,
                                               const float* __restrict__ ea,
                                               unsigned* __restrict__ cursor,
                                               uint2* __restrict__ rec) {
  unsigned e = blockIdx.x * 256u + threadIdx.x;
  unsigned s = (unsigned)ei[e];
  unsigned d = (unsigned)ei[NE + e];
  float w = ea[e];
  unsigned b = d >> 8;
  unsigned pos = atomicAdd(&cursor[b], 1u);
  rec[pos] = make_uint2(s | ((d & 255u) << 21), __float_as_uint(w));
}

// ---------------------------------------------------------------------------
// Conv1 (fused): one dst-bucket per block; ONE RECORD PER THREAD, full x row
// loaded as 4 independent float4s (same 64B line -> 1 line fetch, 4 loads in
// flight back-to-back). Then fused node transform:
// h1 = relu(aggr1@W1_rel + x@W1_root + b1), z2 = h1@W2_rel, r2 = h1@W2_root+b2
// ---------------------------------------------------------------------------
__global__ __launch_bounds__(256) void k_conv1(
    const uint2* __restrict__ rec, const unsigned* __restrict__ base,
    const float* __restrict__ x,
    const float* __restrict__ W1_rel, const float* __restrict__ b1,
    const float* __restrict__ W1_root,
    const float* __restrict__ W2_rel, const float* __restrict__ b2,
    const float* __restrict__ W2_root,
    float* __restrict__ z2, float* __restrict__ r2) {
  __shared__ float acc[RB * STR1];                       // 17408 B
  const int tid = threadIdx.x;
  const unsigned bk = blockIdx.x;
  for (int i = tid; i < RB * STR1; i += 256) acc[i] = 0.f;
  __syncthreads();

  const unsigned r0 = base[bk], r1 = base[bk + 1];
  for (unsigned i = r0 + tid; i < r1; i += 256u) {
    uint2 rv = rec[i];                                   // coalesced 8B
    const float4* xp = reinterpret_cast<const float4*>(x + (size_t)(rv.x & SRCM) * 16);
    float4 v0 = xp[0];                                   // 4 independent loads,
    float4 v1 = xp[1];                                   // one 64B line
    float4 v2 = xp[2];
    float4 v3 = xp[3];
    float w = __uint_as_float(rv.y);
    float* dp = acc + (rv.x >> 21) * STR1;
    atomicAdd(dp + 0,  v0.x * w); atomicAdd(dp + 1,  v0.y * w);
    atomicAdd(dp + 2,  v0.z * w); atomicAdd(dp + 3,  v0.w * w);
    atomicAdd(dp + 4,  v1.x * w); atomicAdd(dp + 5,  v1.y * w);
    atomicAdd(dp + 6,  v1.z * w); atomicAdd(dp + 7,  v1.w * w);
    atomicAdd(dp + 8,  v2.x * w); atomicAdd(dp + 9,  v2.y * w);
    atomicAdd(dp + 10, v2.z * w); atomicAdd(dp + 11, v2.w * w);
    atomicAdd(dp + 12, v3.x * w); atomicAdd(dp + 13, v3.y * w);
    atomicAdd(dp + 14, v3.z * w); atomicAdd(dp + 15, v3.w * w);
  }
  __syncthreads();

  // fused node transform: node n = bk*RB + tid (one node per thread)
  size_t n = (size_t)bk * RB + tid;
  float a[16], xv[16];
  {
    const float4* xp = reinterpret_cast<const float4*>(x + n * 16);
#pragma unroll
    for (int q = 0; q < 4; ++q) {
      float4 t2 = xp[q];
      xv[4*q+0] = t2.x; xv[4*q+1] = t2.y; xv[4*q+2] = t2.z; xv[4*q+3] = t2.w;
    }
#pragma unroll
    for (int i = 0; i < 16; ++i) a[i] = acc[tid * STR1 + i];
  }
  float h[DH];
#pragma unroll
  for (int j = 0; j < DH; ++j) h[j] = b1[j];
#pragma unroll
  for (int i = 0; i < DIN; ++i) {
    float ai = a[i], xi = xv[i];
#pragma unroll
    for (int j = 0; j < DH; ++j)
      h[j] = fmaf(ai, W1_rel[i * DH + j], fmaf(xi, W1_root[i * DH + j], h[j]));
  }
#pragma unroll
  for (int j = 0; j < DH; ++j) h[j] = fmaxf(h[j], 0.f);

  float z[4] = {0.f, 0.f, 0.f, 0.f};
  float r[4] = {b2[0], b2[1], b2[2], b2[3]};
#pragma unroll
  for (int j = 0; j < DH; ++j) {
    float hj = h[j];
#pragma unroll
    for (int k = 0; k < 4; ++k) {
      z[k] = fmaf(hj, W2_rel[j * 4 + k], z[k]);
      r[k] = fmaf(hj, W2_root[j * 4 + k], r[k]);
    }
  }
  *reinterpret_cast<float4*>(z2 + n * 4) = make_float4(z[0], z[1], z[2], z[3]);
  *reinterpret_cast<float4*>(r2 + n * 4) = make_float4(r[0], r[1], r[2], r[3]);
}

// ---------------------------------------------------------------------------
// Conv2 (fused): 1024-node super-bucket per block (4 consecutive 256-buckets,
// contiguous record range). Branch-free 4-record-per-thread unroll for MLP.
// Sub-bucket of a record derived from its slot index vs the interior bases.
// embeds = relu(aggr2 + r2).
// ---------------------------------------------------------------------------
__global__ __launch_bounds__(256) void k_conv2(
    const uint2* __restrict__ rec, const unsigned* __restrict__ base,
    const float* __restrict__ z2, const float* __restrict__ r2,
    float* __restrict__ embeds) {
  __shared__ float acc[RB2 * STR2];                      // 20480 B
  const int tid = threadIdx.x;
  const unsigned bk = blockIdx.x;
  for (int i = tid; i < RB2 * STR2; i += 256) acc[i] = 0.f;
  __syncthreads();

  const unsigned q0 = base[4 * bk + 0];
  const unsigned c1 = base[4 * bk + 1];
  const unsigned c2 = base[4 * bk + 2];
  const unsigned c3 = base[4 * bk + 3];
  const unsigned q4 = base[4 * bk + 4];
  const unsigned cnt = q4 - q0;
  if (cnt) {
    const unsigned last = q4 - 1u;
    const unsigned nch = (cnt + 1023u) >> 10;            // chunks incl. partial
    for (unsigned c = 0; c < nch; ++c) {
      const unsigned i0 = q0 + c * 1024u + tid;
      const unsigned i1 = i0 + 256u, i2 = i0 + 512u, i3 = i0 + 768u;
      const bool b0 = i0 < q4, b1v = i1 < q4, b2v = i2 < q4, b3v = i3 < q4;
      const unsigned j0 = b0  ? i0 : last;
      const unsigned j1 = b1v ? i1 : last;
      const unsigned j2 = b2v ? i2 : last;
      const unsigned j3 = b3v ? i3 : last;
      uint2 ra = rec[j0];                                // 4 coalesced rec loads
      uint2 rb = rec[j1];
      uint2 rc = rec[j2];
      uint2 rd = rec[j3];
      const float4 za = *reinterpret_cast<const float4*>(z2 + (size_t)(ra.x & SRCM) * 4);
      const float4 zb = *reinterpret_cast<const float4*>(z2 + (size_t)(rb.x & SRCM) * 4);
      const float4 zc = *reinterpret_cast<const float4*>(z2 + (size_t)(rc.x & SRCM) * 4);
      const float4 zd = *reinterpret_cast<const float4*>(z2 + (size_t)(rd.x & SRCM) * 4);
      const float wa = b0  ? __uint_as_float(ra.y) : 0.f;
      const float wb = b1v ? __uint_as_float(rb.y) : 0.f;
      const float wc = b2v ? __uint_as_float(rc.y) : 0.f;
      const float wd = b3v ? __uint_as_float(rd.y) : 0.f;
      const unsigned sa = (unsigned)(j0 >= c1) + (j0 >= c2) + (j0 >= c3);
      const unsigned sb = (unsigned)(j1 >= c1) + (j1 >= c2) + (j1 >= c3);
      const unsigned sc = (unsigned)(j2 >= c1) + (j2 >= c2) + (j2 >= c3);
      const unsigned sd = (unsigned)(j3 >= c1) + (j3 >= c2) + (j3 >= c3);
      float* da = acc + (sa * 256u + (ra.x >> 21)) * STR2;
      float* db = acc + (sb * 256u + (rb.x >> 21)) * STR2;
      float* dc = acc + (sc * 256u + (rc.x >> 21)) * STR2;
      float* dd = acc + (sd * 256u + (rd.x >> 21)) * STR2;
      atomicAdd(da + 0, za.x * wa); atomicAdd(da + 1, za.y * wa);
      atomicAdd(da + 2, za.z * wa); atomicAdd(da + 3, za.w * wa);
      atomicAdd(db + 0, zb.x * wb); atomicAdd(db + 1, zb.y * wb);
      atomicAdd(db + 2, zb.z * wb); atomicAdd(db + 3, zb.w * wb);
      atomicAdd(dc + 0, zc.x * wc); atomicAdd(dc + 1, zc.y * wc);
      atomicAdd(dc + 2, zc.z * wc); atomicAdd(dc + 3, zc.w * wc);
      atomicAdd(dd + 0, zd.x * wd); atomicAdd(dd + 1, zd.y * wd);
      atomicAdd(dd + 2, zd.z * wd); atomicAdd(dd + 3, zd.w * wd);
    }
  }
  __syncthreads();

#pragma unroll
  for (int q = 0; q < 4; ++q) {
    const int m = q * 256 + tid;
    const size_t n = (size_t)bk * RB2 + m;
    const float4 rr = *reinterpret_cast<const float4*>(r2 + n * 4);
    float4 o;
    o.x = fmaxf(acc[m * STR2 + 0] + rr.x, 0.f);
    o.y = fmaxf(acc[m * STR2 + 1] + rr.y, 0.f);
    o.z = fmaxf(acc[m * STR2 + 2] + rr.z, 0.f);
    o.w = fmaxf(acc[m * STR2 + 3] + rr.w, 0.f);
    *reinterpret_cast<float4*>(embeds + n * 4) = o;
  }
}

// ---------------------------------------------------------------------------
// Final: per-board  vec = concat(embeds[b,216], gMLP(globalFeats[b]))  [232]
//        out = relu(vec@Wo1+bo1) -> relu(@Wo2+bo2) -> @Wo3+bo3  [64]
// ---------------------------------------------------------------------------
__global__ __launch_bounds__(256) void k_final(
    const float* __restrict__ embeds, const float* __restrict__ gfeat,
    const float* __restrict__ Wg1, const float* __restrict__ bg1,
    const float* __restrict__ Wg2, const float* __restrict__ bg2,
    const float* __restrict__ Wg3, const float* __restrict__ bg3,
    const float* __restrict__ Wo1, const float* __restrict__ bo1,
    const float* __restrict__ Wo2, const float* __restrict__ bo2,
    const float* __restrict__ Wo3, const float* __restrict__ bo3,
    float* __restrict__ out) {
  __shared__ float smem[TB * 232 + TB * 128];   // 46080 B
  float* svec  = smem;             // [TB][232]
  float* sbuf1 = smem + TB * 232;  // [TB][128]
  float* sbuf2 = smem;             // alias svec (dead after layer 1)

  const int tid = threadIdx.x;
  const int b0  = blockIdx.x * TB;

  // stage embeds (already relu'd)
  {
    const size_t gbase = (size_t)b0 * 216;
    for (int idx = tid; idx < TB * 216; idx += 256) {
      int b = idx / 216;
      int k = idx - b * 216;
      svec[b * 232 + k] = embeds[gbase + idx];
    }
  }
  // tiny global-feature MLP: 16 -> 8 -> 8 -> 16 (relu each)
  if (tid < TB) {
    const float* gf = gfeat + (size_t)(b0 + tid) * GLOBF;
    float gin[16];
#pragma unroll
    for (int i = 0; i < 16; ++i) gin[i] = gf[i];
    float g1[8];
#pragma unroll
    for (int j = 0; j < 8; ++j) {
      float acc = bg1[j];
#pragma unroll
      for (int i = 0; i < 16; ++i) acc = fmaf(gin[i], Wg1[i * 8 + j], acc);
      g1[j] = fmaxf(acc, 0.f);
    }
    float g2[8];
#pragma unroll
    for (int j = 0; j < 8; ++j) {
      float acc = bg2[j];
#pragma unroll
      for (int i = 0; i < 8; ++i) acc = fmaf(g1[i], Wg2[i * 8 + j], acc);
      g2[j] = fmaxf(acc, 0.f);
    }
#pragma unroll
    for (int j = 0; j < 16; ++j) {
      float acc = bg3[j];
#pragma unroll
      for (int i = 0; i < 8; ++i) acc = fmaf(g2[i], Wg3[i * 16 + j], acc);
      svec[tid * 232 + 216 + j] = fmaxf(acc, 0.f);
    }
  }
  __syncthreads();

  const int c0 = (tid & 31) * 4;   // output column base (0..124)
  const int rb = (tid >> 5) * 4;   // board base within tile (0..28)

  // layer 1: [TB,232] @ [232,128]
  {
    float acc[4][4];
#pragma unroll
    for (int r = 0; r < 4; ++r)
#pragma unroll
      for (int c = 0; c < 4; ++c) acc[r][c] = 0.f;
#pragma unroll 4
    for (int i = 0; i < 232; ++i) {
      const float4 w = *reinterpret_cast<const float4*>(Wo1 + (size_t)i * 128 + c0);
#pragma unroll
      for (int r = 0; r < 4; ++r) {
        float v = svec[(rb + r) * 232 + i];
        acc[r][0] = fmaf(v, w.x, acc[r][0]);
        acc[r][1] = fmaf(v, w.y, acc[r][1]);
        acc[r][2] = fmaf(v, w.z, acc[r][2]);
        acc[r][3] = fmaf(v, w.w, acc[r][3]);
      }
    }
    const float4 bv = *reinterpret_cast<const float4*>(bo1 + c0);
#pragma unroll
    for (int r = 0; r < 4; ++r) {
      float4 o;
      o.x = fmaxf(acc[r][0] + bv.x, 0.f);
      o.y = fmaxf(acc[r][1] + bv.y, 0.f);
      o.z = fmaxf(acc[r][2] + bv.z, 0.f);
      o.w = fmaxf(acc[r][3] + bv.w, 0.f);
      *reinterpret_cast<float4*>(sbuf1 + (rb + r) * 128 + c0) = o;
    }
  }
  __syncthreads();

  // layer 2: [TB,128] @ [128,128]
  {
    float acc[4][4];
#pragma unroll
    for (int r = 0; r < 4; ++r)
#pragma unroll
      for (int c = 0; c < 4; ++c) acc[r][c] = 0.f;
#pragma unroll 4
    for (int i = 0; i < 128; ++i) {
      const float4 w = *reinterpret_cast<const float4*>(Wo2 + (size_t)i * 128 + c0);
#pragma unroll
      for (int r = 0; r < 4; ++r) {
        float v = sbuf1[(rb + r) * 128 + i];
        acc[r][0] = fmaf(v, w.x, acc[r][0]);
        acc[r][1] = fmaf(v, w.y, acc[r][1]);
        acc[r][2] = fmaf(v, w.z, acc[r][2]);
        acc[r][3] = fmaf(v, w.w, acc[r][3]);
      }
    }
    const float4 bv = *reinterpret_cast<const float4*>(bo2 + c0);
#pragma unroll
    for (int r = 0; r < 4; ++r) {
      float4 o;
      o.x = fmaxf(acc[r][0] + bv.x, 0.f);
      o.y = fmaxf(acc[r][1] + bv.y, 0.f);
      o.z = fmaxf(acc[r][2] + bv.z, 0.f);
      o.w = fmaxf(acc[r][3] + bv.w, 0.f);
      *reinterpret_cast<float4*>(sbuf2 + (rb + r) * 128 + c0) = o;
    }
  }
  __syncthreads();

  // layer 3: [TB,128] @ [128,64] -> global out
  {
    const int c2 = (tid & 31) * 2;   // 0..62
    float acc[4][2];
#pragma unroll
    for (int r = 0; r < 4; ++r) { acc[r][0] = 0.f; acc[r][1] = 0.f; }
#pragma unroll 4
    for (int i = 0; i < 128; ++i) {
      const float2 w = *reinterpret_cast<const float2*>(Wo3 + (size_t)i * 64 + c2);
#pragma unroll
      for (int r = 0; r < 4; ++r) {
        float v = sbuf2[(rb + r) * 128 + i];
        acc[r][0] = fmaf(v, w.x, acc[r][0]);
        acc[r][1] = fmaf(v, w.y, acc[r][1]);
      }
    }
    const float2 bv = *reinterpret_cast<const float2*>(bo3 + c2);
#pragma unroll
    for (int r = 0; r < 4; ++r) {
      float2 o;
      o.x = acc[r][0] + bv.x;
      o.y = acc[r][1] + bv.y;
      *reinterpret_cast<float2*>(out + (size_t)(b0 + rb + r) * 64 + c2) = o;
    }
  }
}

// ---------------------------------------------------------------------------
extern "C" void kernel_launch(void* const* d_in, const int* in_sizes, int n_in,
                              void* d_out, int out_size, void* d_ws, size_t ws_size,
                              hipStream_t stream) {
  const float* x      = (const float*)d_in[0];
  const int*   ei     = (const int*)d_in[1];
  const float* ea     = (const float*)d_in[2];
  const float* gfeat  = (const float*)d_in[3];
  // d_in[4] = isTrain (0 at inference; dropout is identity)
  const float* W1_rel = (const float*)d_in[5];
  const float* b1     = (const float*)d_in[6];
  const float* W1_root= (const float*)d_in[7];
  const float* W2_rel = (const float*)d_in[8];
  const float* b2     = (const float*)d_in[9];
  const float* W2_root= (const float*)d_in[10];
  const float* Wg1 = (const float*)d_in[11];
  const float* bg1 = (const float*)d_in[12];
  const float* Wg2 = (const float*)d_in[13];
  const float* bg2 = (const float*)d_in[14];
  const float* Wg3 = (const float*)d_in[15];
  const float* bg3 = (const float*)d_in[16];
  const float* Wo1 = (const float*)d_in[17];
  const float* bo1 = (const float*)d_in[18];
  const float* Wo2 = (const float*)d_in[19];
  const float* bo2 = (const float*)d_in[20];
  const float* Wo3 = (const float*)d_in[21];
  const float* bo3 = (const float*)d_in[22];
  float* outp = (float*)d_out;

  // workspace layout (~123 MB total)
  uint2*    rec    = (uint2*)d_ws;                       // NE * 8 B
  float*    z2     = (float*)(rec + NE);                 // NN*4 f
  float*    r2     = z2 + (size_t)NN * 4;                // NN*4 f
  float*    embeds = r2 + (size_t)NN * 4;                // NN*4 f
  unsigned* hist   = (unsigned*)(embeds + (size_t)NN * 4); // NBK
  unsigned* base   = hist + NBK;                         // NBK+1
  unsigned* cursor = base + NBK + 1;                     // NBK

  hipMemsetAsync(hist, 0, NBK * sizeof(unsigned), stream);
  k_hist <<<NE / 256, 256, 0, stream>>>(ei, hist);
  k_scan <<<1, 1024, 0, stream>>>(hist, base, cursor);
  k_place<<<NE / 256, 256, 0, stream>>>(ei, ea, cursor, rec);
  k_conv1<<<NBK, 256, 0, stream>>>(rec, base, x, W1_rel, b1, W1_root,
                                   W2_rel, b2, W2_root, z2, r2);
  k_conv2<<<NBK2, 256, 0, stream>>>(rec, base, z2, r2, embeds);
  k_final<<<BD / TB, 256, 0, stream>>>(embeds, gfeat,
                                       Wg1, bg1, Wg2, bg2, Wg3, bg3,
                                       Wo1, bo1, Wo2, bo2, Wo3, bo3, outp);
}